// Round 6
// baseline (118.040 us; speedup 1.0000x reference)
//
#include <hip/hip_runtime.h>
#include <cstdint>

// ChessGNN forward, MI355X.
// R5: LDS cut to 40,832B -> 4 blocks/CU (32 waves, 2048 blocks = 2 exact
//     rounds). W/inW/a_src/a_dst read from global (L2-cached). shF pitch 68
//     (C-store 2-way), sPh vector writes. f16 sSrc/sDst. shfl-based BN reduce.

#define BB   2048
#define NN   90
#define NP   96
#define CC   64
#define NH   4
#define HD   16
#define TPB  512
#define DOUT 128
#define SXP  72      // sx row pitch (f16)
#define SHP  68      // shF row pitch (f32)
#define PPITCH 20    // sPh row pitch (f16), rows 40B (8B aligned)
#define NSLOT 19

typedef _Float16 f16;
typedef _Float16 f16x4 __attribute__((ext_vector_type(4)));
typedef _Float16 f16x8 __attribute__((ext_vector_type(8)));
typedef float f32x4 __attribute__((ext_vector_type(4)));
union U16x4 { f16x4 v; f16 e[4]; };

// LDS map (bytes), total 40,832:
//   [0, 24480)      shF f32[90][68]; sx f16[96][72] overlay [0,13824)
//   [24480, 38880)  uni: L0 sXr f16[90][17] (3060) | sPh f16[360][20] (14400)
//                        | ph7 sRa f32[8][64] (2048) + sRb (2048)
//   [38880, 39600)  sSrc f16[360] (+pad)
//   [39600, 40320)  sDst f16[360] (+pad)
//   [40320, 40832)  sST f32[128]
#define LDS_BYTES 40832

template <int LAYER>
__global__ __launch_bounds__(TPB, 8) void k_gat(
    const float* __restrict__ bp,
    const float* __restrict__ inW,
    const float* __restrict__ inb,
    const float* __restrict__ prevPre,
    const float* __restrict__ stPrev,
    const float* __restrict__ Wl,
    const float* __restrict__ asrc,
    const float* __restrict__ adst,
    float* __restrict__ outPre,
    float* __restrict__ partial,
    float* __restrict__ partialSq)
{
    __shared__ __align__(16) unsigned char lds[LDS_BYTES];
    float* shF  = (float*)lds;                  // [90][68] f32
    f16*   sx   = (f16*)lds;                    // [96][72] f16 (overlay)
    unsigned char* uni = lds + 24480;
    f16*   sXr  = (f16*)uni;                    // [90][17] (L0, phases 1-2)
    f16*   sPh  = (f16*)uni;                    // [360][20] (phases 5-6)
    float* sRa  = (float*)uni;                  // [8][64] (phase 7)
    float* sRb  = (float*)(uni + 2048);
    f16*   sSrcH = (f16*)(lds + 38880);         // [360]
    f16*   sDstH = (f16*)(lds + 39600);         // [360]
    float* sST   = (float*)(lds + 40320);       // [128]

    const int b = blockIdx.x, t = threadIdx.x;
    const int cq = t & 15, ng = t >> 4;
    const int c4 = cq << 2;
    const int jcnt = (ng < NN - 64) ? 3 : 2;
    const int lane = t & 63, wv = t >> 6;
    const int lr = lane & 15, lg = lane >> 4;

    // ---------------- phase 1: stage per-block inputs; zero-pad sx rows 90-95
    if (t < (NP - NN) * (SXP / 4)) {
        int r = t / (SXP / 4), q = t - r * (SXP / 4);
        f16x4 z = {(f16)0, (f16)0, (f16)0, (f16)0};
        *(f16x4*)&sx[(NN + r) * SXP + q * 4] = z;
    }
    if (LAYER == 0) {
        const float* bpb = bp + (size_t)b * (14 * NN);
        for (int i = t; i < 14 * NN; i += TPB) {
            int p = i / NN, n = i - p * NN;
            sXr[n * 17 + p] = (f16)bpb[i];
        }
        if (t < NN) {
            int y = t / 9, x = t - y * 9;
            sXr[t * 17 + 14] = (f16)((float)x / 9.0f);
            sXr[t * 17 + 15] = (f16)((float)y / 10.0f);
        }
    } else {
        if (t < 2 * CC) sST[t] = stPrev[t];
    }
    __syncthreads();

    // ---------------- phase 2: x -> sx (f16)
    if (LAYER == 0) {
        const int n0 = ng, n1 = ng + 32, n2 = (jcnt == 3) ? ng + 64 : ng;
        const float4* inW4 = (const float4*)inW;
        float acc[3][4] = {};
        #pragma unroll 4
        for (int k = 0; k < 16; k++) {
            float4 w = inW4[k * 16 + cq];
            float x0 = (float)sXr[n0 * 17 + k];
            float x1 = (float)sXr[n1 * 17 + k];
            float x2 = (float)sXr[n2 * 17 + k];
            acc[0][0] = fmaf(x0, w.x, acc[0][0]); acc[0][1] = fmaf(x0, w.y, acc[0][1]);
            acc[0][2] = fmaf(x0, w.z, acc[0][2]); acc[0][3] = fmaf(x0, w.w, acc[0][3]);
            acc[1][0] = fmaf(x1, w.x, acc[1][0]); acc[1][1] = fmaf(x1, w.y, acc[1][1]);
            acc[1][2] = fmaf(x1, w.z, acc[1][2]); acc[1][3] = fmaf(x1, w.w, acc[1][3]);
            acc[2][0] = fmaf(x2, w.x, acc[2][0]); acc[2][1] = fmaf(x2, w.y, acc[2][1]);
            acc[2][2] = fmaf(x2, w.z, acc[2][2]); acc[2][3] = fmaf(x2, w.w, acc[2][3]);
        }
        float4 bias = *(const float4*)&inb[c4];
        for (int j = 0; j < jcnt; j++) {
            int n = ng + 32 * j;
            f16x4 o;
            o.x = (f16)(acc[j][0] + bias.x);
            o.y = (f16)(acc[j][1] + bias.y);
            o.z = (f16)(acc[j][2] + bias.z);
            o.w = (f16)(acc[j][3] + bias.w);
            *(f16x4*)&sx[n * SXP + c4] = o;
        }
    } else {
        const float4* pv4 = (const float4*)(prevPre + (size_t)b * (NN * CC));
        for (int i4 = t; i4 < NN * CC / 4; i4 += TPB) {
            float4 v = pv4[i4];
            int n = i4 >> 4, c = (i4 & 15) << 2;
            float a0 = fmaf(v.x, sST[c + 0], sST[CC + c + 0]);
            float a1 = fmaf(v.y, sST[c + 1], sST[CC + c + 1]);
            float a2 = fmaf(v.z, sST[c + 2], sST[CC + c + 2]);
            float a3 = fmaf(v.w, sST[c + 3], sST[CC + c + 3]);
            f16x4 o;
            o.x = (f16)(a0 > 0.0f ? a0 : 0.0f);
            o.y = (f16)(a1 > 0.0f ? a1 : 0.0f);
            o.z = (f16)(a2 > 0.0f ? a2 : 0.0f);
            o.w = (f16)(a3 > 0.0f ? a3 : 0.0f);
            *(f16x4*)&sx[n * SXP + c] = o;
        }
    }
    __syncthreads();

    // ---------------- phase 3: h = x @ W via MFMA; B-frags from global W
    {
        const int nt = wv & 3, m0 = wv >> 2;
        // B fragments straight from global f32 W (L2-cached, same for all blocks)
        f16x8 bf0, bf1;
        #pragma unroll
        for (int j = 0; j < 8; j++) {
            bf0[j] = (f16)Wl[(lg * 8 + j) * CC + nt * 16 + lr];
            bf1[j] = (f16)Wl[(lg * 8 + j + 32) * CC + nt * 16 + lr];
        }
        // A fragments from sx (preload before overlay barrier)
        f16x8 af0[3], af1[3];
        #pragma unroll
        for (int mi = 0; mi < 3; mi++) {
            const int mt = m0 + 2 * mi;
            af0[mi] = *(const f16x8*)&sx[(mt * 16 + lr) * SXP + lg * 8];
            af1[mi] = *(const f16x8*)&sx[(mt * 16 + lr) * SXP + 32 + lg * 8];
        }
        __syncthreads();   // all sx reads done; shF writes may begin
        #pragma unroll
        for (int mi = 0; mi < 3; mi++) {
            const int mt = m0 + 2 * mi;
            f32x4 acc = {0.0f, 0.0f, 0.0f, 0.0f};
            acc = __builtin_amdgcn_mfma_f32_16x16x32_f16(af0[mi], bf0, acc, 0, 0, 0);
            acc = __builtin_amdgcn_mfma_f32_16x16x32_f16(af1[mi], bf1, acc, 0, 0, 0);
            const int row = mt * 16 + lg * 4, col = nt * 16 + lr;
            #pragma unroll
            for (int r = 0; r < 4; r++)
                if (row + r < NN) shF[(row + r) * SHP + col] = acc[r];
        }
    }
    __syncthreads();

    // ---------------- phase 4: attention scores -> sSrc/sDst (f16)
    if (t < NH * NN) {
        int hh = t / NN, n = t - hh * NN;
        const float4* hv = (const float4*)&shF[n * SHP + hh * HD];
        const float4* av = (const float4*)(asrc + hh * HD);
        const float4* dv = (const float4*)(adst + hh * HD);
        float a = 0.0f, d = 0.0f;
        #pragma unroll
        for (int m = 0; m < 4; m++) {
            float4 h4 = hv[m], am = av[m], dm = dv[m];
            a = fmaf(h4.x, am.x, a); a = fmaf(h4.y, am.y, a);
            a = fmaf(h4.z, am.z, a); a = fmaf(h4.w, am.w, a);
            d = fmaf(h4.x, dm.x, d); d = fmaf(h4.y, dm.y, d);
            d = fmaf(h4.z, dm.z, d); d = fmaf(h4.w, dm.w, d);
        }
        sSrcH[t] = (f16)a; sDstH[t] = (f16)d;
    }
    __syncthreads();

    // ---------------- phase 5: positional-slot softmax -> sPh (f16, normalized)
    if (t < NH * NN) {
        int hh = t / NN, n = t - hh * NN;
        int y = n / 9, x = n - y * 9;
        float si = (float)sSrcH[t];
        float e[NSLOT];
        #pragma unroll
        for (int xx = 0; xx < 9; xx++) {
            int dx = xx > x ? xx - x : x - xx;
            float ee = si + (float)sDstH[hh * NN + y * 9 + xx];
            ee = ee > 0.0f ? ee : 0.2f * ee;
            e[xx] = (dx <= 4) ? ee : -1e30f;
        }
        #pragma unroll
        for (int yy = 0; yy < 10; yy++) {
            int dy = yy > y ? yy - y : y - yy;
            float ee = si + (float)sDstH[hh * NN + yy * 9 + x];
            ee = ee > 0.0f ? ee : 0.2f * ee;
            e[9 + yy] = (dy >= 1 && dy <= 5) ? ee : -1e30f;
        }
        float m = e[0];
        #pragma unroll
        for (int k = 1; k < NSLOT; k++) m = fmaxf(m, e[k]);
        float p[NSLOT];
        float s = 0.0f;
        #pragma unroll
        for (int k = 0; k < NSLOT; k++) { p[k] = __expf(e[k] - m); s += p[k]; }
        float inv = 1.0f / s;
        f16* pr = &sPh[t * PPITCH];
        #pragma unroll
        for (int q = 0; q < 5; q++) {
            f16x4 o;
            o.x = (f16)(p[4 * q + 0] * inv);
            o.y = (f16)(p[4 * q + 1] * inv);
            o.z = (f16)(p[4 * q + 2] * inv);
            o.w = (4 * q + 3 < NSLOT) ? (f16)(p[4 * q + 3] * inv) : (f16)0;
        }
        // note: q=4 uses p[16..18] + zero pad
        #pragma unroll
        for (int q = 0; q < 5; q++) {
            U16x4 o;
            #pragma unroll
            for (int j = 0; j < 4; j++) {
                int k = 4 * q + j;
                o.e[j] = (k < NSLOT) ? (f16)(p[k] * inv) : (f16)0;
            }
            *(f16x4*)&pr[4 * q] = o.v;
        }
    }
    __syncthreads();

    // ---------------- phase 6: out = attn @ h (19 fixed slots, f32 h)
    const int hh2 = cq >> 2;
    float lsum[4] = {}, lsq[4] = {};
    float* op = outPre + (size_t)b * (NN * CC);
    for (int j = 0; j < jcnt; j++) {
        int n = ng + 32 * j;
        int y = n / 9, x = n - y * 9;
        const f16* pr = &sPh[(hh2 * NN + n) * PPITCH];
        U16x4 P0, P1, P2, P3, P4;
        P0.v = *(const f16x4*)&pr[0];
        P1.v = *(const f16x4*)&pr[4];
        P2.v = *(const f16x4*)&pr[8];
        P3.v = *(const f16x4*)&pr[12];
        P4.v = *(const f16x4*)&pr[16];
        float a0 = 0.0f, a1 = 0.0f, a2 = 0.0f, a3 = 0.0f;
        #pragma unroll
        for (int xx = 0; xx < 9; xx++) {
            float p = (xx < 4) ? (float)P0.e[xx]
                    : (xx < 8) ? (float)P1.e[xx - 4] : (float)P2.e[0];
            float4 h4 = *(const float4*)&shF[(y * 9 + xx) * SHP + c4];
            a0 = fmaf(p, h4.x, a0); a1 = fmaf(p, h4.y, a1);
            a2 = fmaf(p, h4.z, a2); a3 = fmaf(p, h4.w, a3);
        }
        #pragma unroll
        for (int yy = 0; yy < 10; yy++) {
            int k = 9 + yy;
            float p = (k < 12) ? (float)P2.e[k - 8]
                    : (k < 16) ? (float)P3.e[k - 12] : (float)P4.e[k - 16];
            float4 h4 = *(const float4*)&shF[(yy * 9 + x) * SHP + c4];
            a0 = fmaf(p, h4.x, a0); a1 = fmaf(p, h4.y, a1);
            a2 = fmaf(p, h4.z, a2); a3 = fmaf(p, h4.w, a3);
        }
        float4 o; o.x = a0; o.y = a1; o.z = a2; o.w = a3;
        *(float4*)&op[n * CC + c4] = o;
        lsum[0] += a0; lsum[1] += a1; lsum[2] += a2; lsum[3] += a3;
        lsq[0] = fmaf(a0, a0, lsq[0]); lsq[1] = fmaf(a1, a1, lsq[1]);
        lsq[2] = fmaf(a2, a2, lsq[2]); lsq[3] = fmaf(a3, a3, lsq[3]);
    }
    __syncthreads();   // sPh dead beyond here

    // ---------------- phase 7: BN partials (shfl over ng-subgroups, 4KB buf)
    #pragma unroll
    for (int q = 0; q < 4; q++) {
        float v = lsum[q];
        v += __shfl_xor(v, 16); v += __shfl_xor(v, 32);
        lsum[q] = v;
        float w2 = lsq[q];
        w2 += __shfl_xor(w2, 16); w2 += __shfl_xor(w2, 32);
        lsq[q] = w2;
    }
    if (lg == 0) {
        float4 a; a.x = lsum[0]; a.y = lsum[1]; a.z = lsum[2]; a.w = lsum[3];
        float4 c; c.x = lsq[0]; c.y = lsq[1]; c.z = lsq[2]; c.w = lsq[3];
        *(float4*)&sRa[wv * CC + c4] = a;
        *(float4*)&sRb[wv * CC + c4] = c;
    }
    __syncthreads();
    if (t < CC) {
        float s = 0.0f, q2 = 0.0f;
        #pragma unroll
        for (int g = 0; g < 8; g++) {
            s  += sRa[g * CC + t];
            q2 += sRb[g * CC + t];
        }
        partial[(size_t)b * CC + t] = s;
        partialSq[(size_t)b * CC + t] = q2;
    }
}

// ------------------------------------------------------------- BN statistics
__global__ __launch_bounds__(256) void k_stats(
    const float* __restrict__ partial, const float* __restrict__ partialSq,
    const float* __restrict__ gamma, const float* __restrict__ beta,
    float* __restrict__ st)
{
    const int c = blockIdx.x, t = threadIdx.x;
    float s = 0.0f, q = 0.0f;
    for (int b = t; b < BB; b += 256) {
        s += partial[(size_t)b * CC + c];
        q += partialSq[(size_t)b * CC + c];
    }
    __shared__ float rs[256], rq[256];
    rs[t] = s; rq[t] = q;
    __syncthreads();
    for (int o = 128; o > 0; o >>= 1) {
        if (t < o) { rs[t] += rs[t + o]; rq[t] += rq[t + o]; }
        __syncthreads();
    }
    if (t == 0) {
        const float cntInv = 1.0f / (float)(BB * NN);
        float mean = rs[0] * cntInv;
        float var  = rq[0] * cntInv - mean * mean;
        float sc = gamma[c] * rsqrtf(var + 1e-5f);
        st[c] = sc;
        st[CC + c] = beta[c] - mean * sc;
    }
}

// ------------------------------------------------------------------- final
__global__ __launch_bounds__(256) void k_final(
    const float* __restrict__ pre, const float* __restrict__ st,
    const float* __restrict__ outW, const float* __restrict__ outb,
    float* __restrict__ out)
{
    __shared__ float sM[CC];
    __shared__ float sPart[4][CC];
    const int b = blockIdx.x, t = threadIdx.x;
    const int c = t & 63, p = t >> 6;
    const float* pv = pre + (size_t)b * (NN * CC);
    float s = st[c], sft = st[CC + c];
    float a = 0.0f;
    int nBeg = p * 23, nEnd = nBeg + 23 < NN ? nBeg + 23 : NN;
    for (int n = nBeg; n < nEnd; n++) {
        float v = fmaf(pv[n * CC + c], s, sft);
        a += (v > 0.0f ? v : 0.0f);
    }
    sPart[p][c] = a;
    __syncthreads();
    if (t < CC)
        sM[t] = (sPart[0][t] + sPart[1][t] + sPart[2][t] + sPart[3][t]) * (1.0f / (float)NN);
    __syncthreads();
    if (t < DOUT) {
        float acc = outb[t];
        #pragma unroll
        for (int cc2 = 0; cc2 < CC; cc2++) acc = fmaf(sM[cc2], outW[cc2 * DOUT + t], acc);
        out[(size_t)b * DOUT + t] = acc;
    }
}

// ------------------------------------------------------------------ launch
extern "C" void kernel_launch(void* const* d_in, const int* in_sizes, int n_in,
                              void* d_out, int out_size, void* d_ws, size_t ws_size,
                              hipStream_t stream) {
    (void)in_sizes; (void)n_in; (void)out_size; (void)ws_size;

    const float* bp   = (const float*)d_in[0];
    const float* inW  = (const float*)d_in[1];
    const float* inb  = (const float*)d_in[2];
    const float* W0   = (const float*)d_in[3];
    const float* as0  = (const float*)d_in[4];
    const float* ad0  = (const float*)d_in[5];
    const float* g0   = (const float*)d_in[6];
    const float* b0   = (const float*)d_in[7];
    const float* W1   = (const float*)d_in[8];
    const float* as1  = (const float*)d_in[9];
    const float* ad1  = (const float*)d_in[10];
    const float* g1   = (const float*)d_in[11];
    const float* b1   = (const float*)d_in[12];
    const float* outW = (const float*)d_in[13];
    const float* outb = (const float*)d_in[14];
    float* out = (float*)d_out;

    float* ws = (float*)d_ws;
    float* outPre    = ws;
    float* partial   = outPre + (size_t)BB * NN * CC;
    float* partialSq = partial + (size_t)BB * CC;
    float* st0       = partialSq + (size_t)BB * CC;
    float* st1       = st0 + 2 * CC;

    k_gat<0><<<BB, TPB, 0, stream>>>(bp, inW, inb, nullptr, nullptr,
                                     W0, as0, ad0, outPre, partial, partialSq);
    k_stats<<<CC, 256, 0, stream>>>(partial, partialSq, g0, b0, st0);
    k_gat<1><<<BB, TPB, 0, stream>>>(nullptr, nullptr, nullptr, outPre, st0,
                                     W1, as1, ad1, outPre, partial, partialSq);
    k_stats<<<CC, 256, 0, stream>>>(partial, partialSq, g1, b1, st1);
    k_final<<<BB, 256, 0, stream>>>(outPre, st1, outW, outb, out);
}